// Round 8
// baseline (280.251 us; speedup 1.0000x reference)
//
#include <hip/hip_runtime.h>
#include <math.h>

#define B_SZ 2048
#define DIN  1024
#define H_SZ 4096
#define D_SZ 128
#define P_SZ 1000
#define PPAD 1024

typedef __attribute__((ext_vector_type(8))) short bf16x8;
typedef __attribute__((ext_vector_type(4))) float f32x4;

__device__ __forceinline__ float gelu_exact(float v) {
    return 0.5f * v * (1.0f + erff(v * 0.70710678118654752f));
}

__device__ __forceinline__ short f2bf(float f) {
    unsigned u = __float_as_uint(f);
    u = (u + 0x7fffu + ((u >> 16) & 1u)) >> 16;
    return (short)u;
}

// async global->LDS, 16B per lane. LDS dest = wave-uniform base + lane*16.
__device__ __forceinline__ void gload_lds16(const void* g, void* l) {
    __builtin_amdgcn_global_load_lds(
        (__attribute__((address_space(1))) void*)(uintptr_t)g,
        (__attribute__((address_space(3))) void*)(uintptr_t)l,
        16, 0, 0);
}

// ---------------------------------------------------------------------------
// Fused prep: x->bf16, W1/W2/W3 transpose->bf16, proto pad/convert + a2.
// ---------------------------------------------------------------------------
__device__ __forceinline__ void trans_tile(
    const float* __restrict__ W, short* __restrict__ WT, int K, int N,
    int bx, int by, int tid, float (*t)[65])
{
    const int n0 = bx * 64, k0 = by * 64;
    #pragma unroll
    for (int i = 0; i < 4; ++i) {
        const int idx = i * 256 + tid;          // float4 index
        const int r  = idx >> 4;                // k-row (16 float4 per row)
        const int c4 = (idx & 15) * 4;
        const float4 v = *reinterpret_cast<const float4*>(&W[(size_t)(k0 + r) * N + n0 + c4]);
        t[r][c4 + 0] = v.x; t[r][c4 + 1] = v.y; t[r][c4 + 2] = v.z; t[r][c4 + 3] = v.w;
    }
    __syncthreads();
    #pragma unroll
    for (int i = 0; i < 2; ++i) {
        const int idx = i * 256 + tid;
        const int n  = idx >> 3;                // 8 k-chunks per n-row
        const int kc = (idx & 7) * 8;
        bf16x8 o;
        #pragma unroll
        for (int q = 0; q < 8; ++q) o[q] = f2bf(t[kc + q][n]);
        *reinterpret_cast<bf16x8*>(&WT[(size_t)(n0 + n) * K + k0 + kc]) = o;
    }
}

__global__ __launch_bounds__(256) void prep_kernel(
    const float* __restrict__ x,     short* __restrict__ xb,
    const float* __restrict__ W1,    short* __restrict__ w1t,
    const float* __restrict__ W2,    short* __restrict__ w2t,
    const float* __restrict__ W3,    short* __restrict__ w3t,
    const float* __restrict__ proto, short* __restrict__ protob,
    float* __restrict__ a2gp)
{
    __shared__ float t[64][65];
    __shared__ float part[4];
    const int b = blockIdx.x;
    const int tid = threadIdx.x;

    if (b < 2048) {
        const int i = b * 1024 + tid * 4;
        const float4 v = *reinterpret_cast<const float4*>(&x[i]);
        short4 o;
        o.x = f2bf(v.x); o.y = f2bf(v.y); o.z = f2bf(v.z); o.w = f2bf(v.w);
        *reinterpret_cast<short4*>(&xb[i]) = o;
    } else if (b < 3072) {
        const int tt = b - 2048;                 // 64 x 16 tiles
        trans_tile(W1, w1t, DIN, H_SZ, tt & 63, tt >> 6, tid, t);
    } else if (b < 7168) {
        const int tt = b - 3072;                 // 64 x 64 tiles
        trans_tile(W2, w2t, H_SZ, H_SZ, tt & 63, tt >> 6, tid, t);
    } else if (b < 7296) {
        const int tt = b - 7168;                 // 2 x 64 tiles
        trans_tile(W3, w3t, H_SZ, D_SZ, tt & 1, tt >> 1, tid, t);
    } else {
        const int h = tid >> 7;                  // half-block
        const int d = tid & 127;
        const int p = (b - 7296) * 2 + h;
        const float y = (p < P_SZ) ? proto[(size_t)p * D_SZ + d] : 0.f;
        protob[(size_t)p * D_SZ + d] = f2bf(y);
        float s = y * y;
        #pragma unroll
        for (int off = 32; off; off >>= 1) s += __shfl_down(s, off);
        if ((tid & 63) == 0) part[tid >> 6] = s;
        __syncthreads();
        if (d == 0) a2gp[p] = part[h * 2] + part[h * 2 + 1];
    }
}

// ---------------------------------------------------------------------------
// Big pipelined bf16 MFMA GEMM (round-4/6 PROVEN structure — do not re-graft
// phase splits: r5/r7 both regressed it).
// Tile 256(M) x 128(N), BK=64, 512 threads = 8 waves (4M x 2N), per-wave 64x64.
// 3-deep LDS pipeline, counted vmcnt(6), source-side XOR swizzle.
// EPI 0: gelu(x+bias) -> bf16. EPI 1: split-K plain store to per-z fp32 slice.
// ---------------------------------------------------------------------------
template<int EPI>
__global__ __launch_bounds__(512) void gemm_big(
    const short* __restrict__ A, const short* __restrict__ BT,
    const float* __restrict__ bias, void* __restrict__ Cout,
    int M, int N, int K)
{
    extern __shared__ __align__(16) char smem[];   // 3 * (32KB A + 16KB B)

    const int tid  = threadIdx.x;
    const int lane = tid & 63;
    const int wid  = tid >> 6;
    const int row0 = blockIdx.y * 256;
    const int col0 = blockIdx.x * 128;
    const int wm = (wid >> 1) * 64;    // wave's 64-row slab
    const int wn = (wid & 1) * 64;     // wave's 64-col slab
    const int lr = lane & 15, kq = lane >> 4;

    const int kpb    = K / gridDim.z;  // split-K chunk
    const int kstart = blockIdx.z * kpb;
    const int NT = kpb >> 6;           // K64 tiles in this chunk

    f32x4 acc[4][4];
    #pragma unroll
    for (int i = 0; i < 4; ++i)
        #pragma unroll
        for (int j = 0; j < 4; ++j) acc[i][j] = (f32x4){0.f, 0.f, 0.f, 0.f};

    // per-lane staging source (pre-swizzled k-chunk)
    const int srow = lane >> 3;              // row within 8-row group
    const int kch  = (lane & 7) ^ srow;      // swizzled 16B k-chunk 0..7
    const short* Ag = A  + (size_t)(row0 + wid * 32 + srow) * K + kstart + kch * 8;
    const short* Bg = BT + (size_t)(col0 + wid * 16 + srow) * K + kstart + kch * 8;

    auto stage = [&](int t) {
        const int buf = t % 3;
        char* sA = smem + buf * 49152;
        char* sB = sA + 32768;
        const int k0 = t << 6;
        #pragma unroll
        for (int ii = 0; ii < 4; ++ii)      // A: 256 rows = 32 instr, 4/wave
            gload_lds16(Ag + (size_t)ii * 8 * K + k0, sA + (wid * 4 + ii) * 1024);
        #pragma unroll
        for (int ii = 0; ii < 2; ++ii)      // B: 128 rows = 16 instr, 2/wave
            gload_lds16(Bg + (size_t)ii * 8 * K + k0, sB + (wid * 2 + ii) * 1024);
    };

    stage(0);
    stage(1);
    asm volatile("s_waitcnt vmcnt(6)" ::: "memory");   // tile 0 resident
    __builtin_amdgcn_s_barrier();
    asm volatile("" ::: "memory");

    for (int t = 0; t < NT; ++t) {
        const bool more = (t + 2) < NT;
        if (more) stage(t + 2);             // uniform branch

        const char* sA = smem + (t % 3) * 49152;
        const char* sB = sA + 32768;

        #pragma unroll
        for (int ks = 0; ks < 2; ++ks) {
            bf16x8 af[4], bfv[4];
            #pragma unroll
            for (int i = 0; i < 4; ++i) {
                const int row = wm + i * 16 + lr;
                af[i] = *reinterpret_cast<const bf16x8*>(
                    sA + row * 128 + (((ks * 4 + kq) ^ (lr & 7)) * 16));
            }
            #pragma unroll
            for (int j = 0; j < 4; ++j) {
                const int row = wn + j * 16 + lr;
                bfv[j] = *reinterpret_cast<const bf16x8*>(
                    sB + row * 128 + (((ks * 4 + kq) ^ (lr & 7)) * 16));
            }
            __builtin_amdgcn_s_setprio(1);
            #pragma unroll
            for (int i = 0; i < 4; ++i)
                #pragma unroll
                for (int j = 0; j < 4; ++j)
                    acc[i][j] = __builtin_amdgcn_mfma_f32_16x16x32_bf16(
                        af[i], bfv[j], acc[i][j], 0, 0, 0);
            __builtin_amdgcn_s_setprio(0);
        }

        asm volatile("" ::: "memory");
        if (more) asm volatile("s_waitcnt vmcnt(6) lgkmcnt(0)" ::: "memory");
        else      asm volatile("s_waitcnt vmcnt(0) lgkmcnt(0)" ::: "memory");
        __builtin_amdgcn_s_barrier();
        asm volatile("" ::: "memory");
    }

    // Epilogue. D frag layout: row = (lane>>4)*4 + q, col = lane&15.
    #pragma unroll
    for (int j = 0; j < 4; ++j) {
        const int col = col0 + wn + j * 16 + lr;
        const float bv = (EPI == 0) ? bias[col] : 0.f;
        #pragma unroll
        for (int i = 0; i < 4; ++i) {
            #pragma unroll
            for (int q = 0; q < 4; ++q) {
                const int row = row0 + wm + i * 16 + kq * 4 + q;
                if (EPI == 0) {
                    float v = gelu_exact(acc[i][j][q] + bv);
                    ((short*)Cout)[(size_t)row * N + col] = f2bf(v);
                } else {
                    ((float*)Cout)[((size_t)blockIdx.z * M + row) * N + col] = acc[i][j][q];
                }
            }
        }
    }
}

// ---------------------------------------------------------------------------
// OCCUPANCY EXPERIMENT (GEMM1 only): 128x128 tile, BK=32, 256 thr = 4 waves,
// 3-deep pipeline (48KB static LDS -> 2 blocks/CU at grid 512), counted
// vmcnt(4). LDS kq-major [buf][kq][row][8]: frag reads are 256B-contiguous
// per 16-lane group -> conflict-free without swizzle (r3: 0 conflicts).
// ---------------------------------------------------------------------------
__global__ __launch_bounds__(256) void gemm_m128(
    const short* __restrict__ A, const short* __restrict__ BT,
    const float* __restrict__ bias, short* __restrict__ Cout,
    int M, int N, int K)
{
    __shared__ __align__(16) short sA[3][4][128][8];  // 3 x 8KB
    __shared__ __align__(16) short sB[3][4][128][8];  // 3 x 8KB

    const int tid  = threadIdx.x;
    const int lane = tid & 63;
    const int wid  = tid >> 6;
    const int row0 = blockIdx.y * 128;
    const int col0 = blockIdx.x * 128;
    const int wm = (wid >> 1) * 64;
    const int wn = (wid & 1) * 64;
    const int lr = lane & 15, kq = lane >> 4;

    const int NT = K >> 5;             // K32 tiles

    f32x4 acc[4][4];
    #pragma unroll
    for (int i = 0; i < 4; ++i)
        #pragma unroll
        for (int j = 0; j < 4; ++j) acc[i][j] = (f32x4){0.f, 0.f, 0.f, 0.f};

    // wave w stages k-group w: lane covers one row (16B = 8 bf16 of k)
    const short* Ag = A  + (size_t)(row0 + lane) * K + wid * 8;
    const short* Bg = BT + (size_t)(col0 + lane) * K + wid * 8;

    auto stage = [&](int t) {
        const int buf = t % 3;
        const int k0 = t << 5;
        #pragma unroll
        for (int ii = 0; ii < 2; ++ii) {   // A: 128 rows = 2 instr/wave
            gload_lds16(Ag + (size_t)(ii * 64) * K + k0, &sA[buf][wid][ii * 64][0]);
            gload_lds16(Bg + (size_t)(ii * 64) * K + k0, &sB[buf][wid][ii * 64][0]);
        }
    };

    stage(0);
    stage(1);
    asm volatile("s_waitcnt vmcnt(4)" ::: "memory");   // tile 0 resident
    __builtin_amdgcn_s_barrier();
    asm volatile("" ::: "memory");

    for (int t = 0; t < NT; ++t) {
        const bool more = (t + 2) < NT;
        if (more) stage(t + 2);
        const int buf = t % 3;

        bf16x8 af[4], bfv[4];
        #pragma unroll
        for (int i = 0; i < 4; ++i)
            af[i] = *reinterpret_cast<const bf16x8*>(&sA[buf][kq][wm + i * 16 + lr][0]);
        #pragma unroll
        for (int j = 0; j < 4; ++j)
            bfv[j] = *reinterpret_cast<const bf16x8*>(&sB[buf][kq][wn + j * 16 + lr][0]);

        __builtin_amdgcn_s_setprio(1);
        #pragma unroll
        for (int i = 0; i < 4; ++i)
            #pragma unroll
            for (int j = 0; j < 4; ++j)
                acc[i][j] = __builtin_amdgcn_mfma_f32_16x16x32_bf16(
                    af[i], bfv[j], acc[i][j], 0, 0, 0);
        __builtin_amdgcn_s_setprio(0);

        asm volatile("" ::: "memory");
        if (more) asm volatile("s_waitcnt vmcnt(4) lgkmcnt(0)" ::: "memory");
        else      asm volatile("s_waitcnt vmcnt(0) lgkmcnt(0)" ::: "memory");
        __builtin_amdgcn_s_barrier();
        asm volatile("" ::: "memory");
    }

    #pragma unroll
    for (int j = 0; j < 4; ++j) {
        const int col = col0 + wn + j * 16 + lr;
        const float bv = bias[col];
        #pragma unroll
        for (int i = 0; i < 4; ++i) {
            #pragma unroll
            for (int q = 0; q < 4; ++q) {
                const int row = row0 + wm + i * 16 + kq * 4 + q;
                float v = gelu_exact(acc[i][j][q] + bv);
                Cout[(size_t)row * N + col] = f2bf(v);
            }
        }
    }
}

// ---------------------------------------------------------------------------
// expmap0: u = sum_z up[z] + b3 -> x_hyp (bf16) ; rowb2 = tanh(||u||)^2.
// ---------------------------------------------------------------------------
__global__ __launch_bounds__(128) void expmap_kernel(
    const float* __restrict__ up, const float* __restrict__ b3,
    short* __restrict__ xhb, float* __restrict__ rowb2)
{
    const int b = blockIdx.x;
    const int d = threadIdx.x;
    float u = b3[d];
    #pragma unroll
    for (int z = 0; z < 16; ++z)
        u += up[((size_t)z * B_SZ + b) * D_SZ + d];

    float s = u * u;
    #pragma unroll
    for (int off = 32; off; off >>= 1) s += __shfl_down(s, off);
    __shared__ float part[2];
    if ((d & 63) == 0) part[d >> 6] = s;
    __syncthreads();
    const float n2 = part[0] + part[1];

    const float n = fmaxf(sqrtf(n2), 1e-15f);
    const float t = tanhf(n);
    xhb[(size_t)b * D_SZ + d] = f2bf(u * (t / n));
    if (d == 0) rowb2[b] = t * t;
}

// ---------------------------------------------------------------------------
// MFMA pairwise hyperbolic distance -> logits.
// Tile 128(b) x 64(p), 256 threads = 4 waves (2b x 2p of 64x32). K = 128.
// ---------------------------------------------------------------------------
__global__ __launch_bounds__(256) void dist_mfma(
    const short* __restrict__ xhb, const short* __restrict__ protob,
    const float* __restrict__ rowb2, const float* __restrict__ a2gp,
    float* __restrict__ logits)
{
    __shared__ __align__(16) char xs[128 * 256];  // 32 KB [row][256B]
    __shared__ __align__(16) char ps[64 * 256];   // 16 KB

    const int tid  = threadIdx.x;
    const int lane = tid & 63, wid = tid >> 6;
    const int pt = blockIdx.x * 64;
    const int bt = blockIdx.y * 128;
    const int wm = (wid >> 1) * 64;    // b slab
    const int wn = (wid & 1) * 32;     // p slab
    const int lr = lane & 15, kq = lane >> 4;

    // staging: each 1KB gload covers 4 rows x 16 chunks; lane = rl*16 + c
    const int rl = lane >> 4, c = lane & 15;
    #pragma unroll
    for (int i = 0; i < 8; ++i) {          // xh: 32 gloads, 8/wave
        const int row = wid * 32 + i * 4 + rl;
        const int lc  = (c & 8) | ((c & 7) ^ (row & 7));
        gload_lds16(xhb + (size_t)(bt + row) * D_SZ + lc * 8,
                    xs + (wid * 8 + i) * 1024);
    }
    #pragma unroll
    for (int i = 0; i < 4; ++i) {          // proto: 16 gloads, 4/wave
        const int row = wid * 16 + i * 4 + rl;
        const int lc  = (c & 8) | ((c & 7) ^ (row & 7));
        gload_lds16(protob + (size_t)(pt + row) * D_SZ + lc * 8,
                    ps + (wid * 4 + i) * 1024);
    }
    __syncthreads();

    f32x4 acc[4][2];
    #pragma unroll
    for (int i = 0; i < 4; ++i)
        #pragma unroll
        for (int j = 0; j < 2; ++j) acc[i][j] = (f32x4){0.f, 0.f, 0.f, 0.f};

    #pragma unroll
    for (int ks = 0; ks < 4; ++ks) {
        const int kslot = ks * 4 + kq;
        bf16x8 af[4], bfv[2];
        #pragma unroll
        for (int i = 0; i < 4; ++i) {
            const int row = wm + i * 16 + lr;
            const int ph = (kslot & 8) | ((kslot & 7) ^ (row & 7));
            af[i] = *reinterpret_cast<const bf16x8*>(xs + row * 256 + ph * 16);
        }
        #pragma unroll
        for (int j = 0; j < 2; ++j) {
            const int row = wn + j * 16 + lr;
            const int ph = (kslot & 8) | ((kslot & 7) ^ (row & 7));
            bfv[j] = *reinterpret_cast<const bf16x8*>(ps + row * 256 + ph * 16);
        }
        #pragma unroll
        for (int i = 0; i < 4; ++i)
            #pragma unroll
            for (int j = 0; j < 2; ++j)
                acc[i][j] = __builtin_amdgcn_mfma_f32_16x16x32_bf16(
                    af[i], bfv[j], acc[i][j], 0, 0, 0);
    }

    // epilogue: hyperbolic formula, fp32. D frag: row=(lane>>4)*4+q, col=lane&15
    #pragma unroll
    for (int j = 0; j < 2; ++j) {
        const int p = pt + wn + j * 16 + lr;
        if (p < P_SZ) {
            const float a2 = a2gp[p];
            #pragma unroll
            for (int i = 0; i < 4; ++i) {
                #pragma unroll
                for (int q = 0; q < 4; ++q) {
                    const int b = bt + wm + i * 16 + kq * 4 + q;
                    const float b2 = rowb2[b];
                    const float ab = -acc[i][j][q];
                    const float alpha = 1.f + 2.f * ab + b2;
                    const float beta  = 1.f - a2;
                    const float gamma = 1.f + 2.f * ab + a2 * b2;
                    const float num = alpha * alpha * a2 + 2.f * alpha * beta * ab + beta * beta * b2;
                    const float m2 = num / (gamma * gamma);
                    const float mn = sqrtf(fmaxf(m2, 0.f));
                    const float arg = fminf(mn, 0.99999f);              // TANH_CLIP
                    const float dist = logf((1.f + arg) / (1.f - arg)); // 2*atanh
                    logits[(size_t)b * P_SZ + p] = -10.f * dist;        // -dist/TEMP
                }
            }
        }
    }
}

// ---------------------------------------------------------------------------
// Per-row argmax (first-max tie-break) + logmap0(proto[pred]).
// ---------------------------------------------------------------------------
__global__ __launch_bounds__(256) void head_kernel(
    const float* __restrict__ logits, const float* __restrict__ proto,
    float* __restrict__ fb)
{
    const int b = blockIdx.x;
    const int tid = threadIdx.x;

    float best = -INFINITY; int bi = 0;
    for (int p = tid; p < P_SZ; p += 256) {
        const float v = logits[(size_t)b * P_SZ + p];
        if (v > best) { best = v; bi = p; }
    }
    __shared__ float bv[256];
    __shared__ int   bidx[256];
    bv[tid] = best; bidx[tid] = bi;
    __syncthreads();
    for (int s = 128; s; s >>= 1) {
        if (tid < s) {
            const float ov = bv[tid + s]; const int oi = bidx[tid + s];
            if (ov > bv[tid] || (ov == bv[tid] && oi < bidx[tid])) { bv[tid] = ov; bidx[tid] = oi; }
        }
        __syncthreads();
    }
    const int pred = bidx[0];
    __syncthreads();

    float y = 0.f;
    if (tid < 128) y = proto[(size_t)pred * D_SZ + tid];
    bv[tid] = y * y;
    __syncthreads();
    for (int s = 128; s; s >>= 1) {
        if (tid < s) bv[tid] += bv[tid + s];
        __syncthreads();
    }
    const float n2 = bv[0];
    if (tid < 128) {
        const float n = fmaxf(sqrtf(n2), 1e-15f);
        const float arg = fminf(n, 0.99999f);
        const float at = 0.5f * logf((1.f + arg) / (1.f - arg));
        fb[(size_t)b * D_SZ + tid] = at * (y / n);
    }
}

extern "C" void kernel_launch(void* const* d_in, const int* in_sizes, int n_in,
                              void* d_out, int out_size, void* d_ws, size_t ws_size,
                              hipStream_t stream)
{
    const float* x     = (const float*)d_in[0];
    const float* W1    = (const float*)d_in[1];
    const float* b1    = (const float*)d_in[2];
    const float* W2    = (const float*)d_in[3];
    const float* b2v   = (const float*)d_in[4];
    const float* W3    = (const float*)d_in[5];
    const float* b3    = (const float*)d_in[6];
    const float* proto = (const float*)d_in[7];

    float* logits = (float*)d_out;                      // 2048*1000
    float* fb     = logits + (size_t)B_SZ * P_SZ;       // 2048*128

    // workspace layout (bf16 stored as short)
    short* xb     = (short*)d_ws;                        //  2048*1024
    short* w1t    = xb    + (size_t)B_SZ * DIN;          //  4096*1024
    short* w2t    = w1t   + (size_t)H_SZ * DIN;          //  4096*4096
    short* w3t    = w2t   + (size_t)H_SZ * H_SZ;         //   128*4096
    short* h1     = w3t   + (size_t)D_SZ * H_SZ;         //  2048*4096 (bf16)
    short* h2     = h1    + (size_t)B_SZ * H_SZ;         //  2048*4096
    short* xhb    = h2    + (size_t)B_SZ * H_SZ;         //  2048*128 bf16
    short* protob = xhb   + (size_t)B_SZ * D_SZ;         //  1024*128 bf16
    float* rowb2  = (float*)(protob + (size_t)PPAD * D_SZ); // 2048 fp32
    float* a2gp   = rowb2 + B_SZ;                        //  1024 fp32
    // up aliases h1 (dead after GEMM2): 16 slices * 2048*128 fp32 = 16 MB
    float* up     = (float*)h1;

    static_cast<void>(hipFuncSetAttribute(
        reinterpret_cast<const void*>(&gemm_big<0>),
        hipFuncAttributeMaxDynamicSharedMemorySize, 3 * 49152));
    static_cast<void>(hipFuncSetAttribute(
        reinterpret_cast<const void*>(&gemm_big<1>),
        hipFuncAttributeMaxDynamicSharedMemorySize, 3 * 49152));

    // --- fused precision prep (1 launch: cvt + 3 transposes + protos) ---
    prep_kernel<<<7808, 256, 0, stream>>>(x, xb, W1, w1t, W2, w2t, W3, w3t,
                                          proto, protob, a2gp);

    // --- MLP ---
    // GEMM1: occupancy experiment (128^2 tile, 2 blocks/CU, counted vmcnt)
    gemm_m128<<<dim3(H_SZ / 128, B_SZ / 128), 256, 0, stream>>>(
        xb, w1t, b1, h1, B_SZ, H_SZ, DIN);
    // GEMM2: proven round-4/6 structure
    gemm_big<0><<<dim3(H_SZ / 128, B_SZ / 256), 512, 3 * 49152, stream>>>(
        h1, w2t, b2v, h2, B_SZ, H_SZ, H_SZ);
    // GEMM3: split-K=16, per-z slices (no atomics); up aliases h1 (h1 dead now)
    gemm_big<1><<<dim3(1, B_SZ / 256, 16), 512, 3 * 49152, stream>>>(
        h2, w3t, nullptr, up, B_SZ, D_SZ, H_SZ);

    // --- hyperbolic head ---
    expmap_kernel<<<B_SZ, 128, 0, stream>>>(up, b3, xhb, rowb2);
    dist_mfma<<<dim3(PPAD / 64, B_SZ / 128), 256, 0, stream>>>(
        xhb, protob, rowb2, a2gp, logits);
    head_kernel<<<B_SZ, 256, 0, stream>>>(logits, proto, fb);
}

// Round 9
// 276.275 us; speedup vs baseline: 1.0144x; 1.0144x over previous
//
#include <hip/hip_runtime.h>
#include <math.h>

#define B_SZ 2048
#define DIN  1024
#define H_SZ 4096
#define D_SZ 128
#define P_SZ 1000
#define PPAD 1024

typedef __attribute__((ext_vector_type(8))) short bf16x8;
typedef __attribute__((ext_vector_type(4))) float f32x4;

__device__ __forceinline__ float gelu_exact(float v) {
    return 0.5f * v * (1.0f + erff(v * 0.70710678118654752f));
}

__device__ __forceinline__ short f2bf(float f) {
    unsigned u = __float_as_uint(f);
    u = (u + 0x7fffu + ((u >> 16) & 1u)) >> 16;
    return (short)u;
}
__device__ __forceinline__ float bf2f(short s) {
    unsigned u = ((unsigned)(unsigned short)s) << 16;
    return __uint_as_float(u);
}

// async global->LDS, 16B per lane. LDS dest = wave-uniform base + lane*16.
__device__ __forceinline__ void gload_lds16(const void* g, void* l) {
    __builtin_amdgcn_global_load_lds(
        (__attribute__((address_space(1))) void*)(uintptr_t)g,
        (__attribute__((address_space(3))) void*)(uintptr_t)l,
        16, 0, 0);
}

// ---------------------------------------------------------------------------
// Fused prep: x->bf16, W1/W2/W3 transpose->bf16, proto pad/convert + a2.
// ---------------------------------------------------------------------------
__device__ __forceinline__ void trans_tile(
    const float* __restrict__ W, short* __restrict__ WT, int K, int N,
    int bx, int by, int tid, float (*t)[65])
{
    const int n0 = bx * 64, k0 = by * 64;
    #pragma unroll
    for (int i = 0; i < 4; ++i) {
        const int idx = i * 256 + tid;          // float4 index
        const int r  = idx >> 4;                // k-row (16 float4 per row)
        const int c4 = (idx & 15) * 4;
        const float4 v = *reinterpret_cast<const float4*>(&W[(size_t)(k0 + r) * N + n0 + c4]);
        t[r][c4 + 0] = v.x; t[r][c4 + 1] = v.y; t[r][c4 + 2] = v.z; t[r][c4 + 3] = v.w;
    }
    __syncthreads();
    #pragma unroll
    for (int i = 0; i < 2; ++i) {
        const int idx = i * 256 + tid;
        const int n  = idx >> 3;                // 8 k-chunks per n-row
        const int kc = (idx & 7) * 8;
        bf16x8 o;
        #pragma unroll
        for (int q = 0; q < 8; ++q) o[q] = f2bf(t[kc + q][n]);
        *reinterpret_cast<bf16x8*>(&WT[(size_t)(n0 + n) * K + k0 + kc]) = o;
    }
}

__global__ __launch_bounds__(256) void prep_kernel(
    const float* __restrict__ x,     short* __restrict__ xb,
    const float* __restrict__ W1,    short* __restrict__ w1t,
    const float* __restrict__ W2,    short* __restrict__ w2t,
    const float* __restrict__ W3,    short* __restrict__ w3t,
    const float* __restrict__ proto, short* __restrict__ protob,
    float* __restrict__ a2gp)
{
    __shared__ float t[64][65];
    __shared__ float part[4];
    const int b = blockIdx.x;
    const int tid = threadIdx.x;

    if (b < 2048) {
        const int i = b * 1024 + tid * 4;
        const float4 v = *reinterpret_cast<const float4*>(&x[i]);
        short4 o;
        o.x = f2bf(v.x); o.y = f2bf(v.y); o.z = f2bf(v.z); o.w = f2bf(v.w);
        *reinterpret_cast<short4*>(&xb[i]) = o;
    } else if (b < 3072) {
        const int tt = b - 2048;                 // 64 x 16 tiles
        trans_tile(W1, w1t, DIN, H_SZ, tt & 63, tt >> 6, tid, t);
    } else if (b < 7168) {
        const int tt = b - 3072;                 // 64 x 64 tiles
        trans_tile(W2, w2t, H_SZ, H_SZ, tt & 63, tt >> 6, tid, t);
    } else if (b < 7296) {
        const int tt = b - 7168;                 // 2 x 64 tiles
        trans_tile(W3, w3t, H_SZ, D_SZ, tt & 1, tt >> 1, tid, t);
    } else {
        const int h = tid >> 7;                  // half-block
        const int d = tid & 127;
        const int p = (b - 7296) * 2 + h;
        const float y = (p < P_SZ) ? proto[(size_t)p * D_SZ + d] : 0.f;
        protob[(size_t)p * D_SZ + d] = f2bf(y);
        float s = y * y;
        #pragma unroll
        for (int off = 32; off; off >>= 1) s += __shfl_down(s, off);
        if ((tid & 63) == 0) part[tid >> 6] = s;
        __syncthreads();
        if (d == 0) a2gp[p] = part[h * 2] + part[h * 2 + 1];
    }
}

// ---------------------------------------------------------------------------
// Big pipelined bf16 MFMA GEMM (round-4/6 PROVEN structure).
// Tile 256(M) x 128(N), BK=64, 512 threads = 8 waves (4M x 2N), per-wave 64x64.
// 3-deep LDS pipeline, counted vmcnt(6), source-side XOR swizzle.
// EPI 0: gelu(x+bias) -> bf16. EPI 1: split-K plain store to per-z fp32 slice.
// ---------------------------------------------------------------------------
template<int EPI>
__global__ __launch_bounds__(512) void gemm_big(
    const short* __restrict__ A, const short* __restrict__ BT,
    const float* __restrict__ bias, void* __restrict__ Cout,
    int M, int N, int K)
{
    extern __shared__ __align__(16) char smem[];   // 3 * (32KB A + 16KB B)

    const int tid  = threadIdx.x;
    const int lane = tid & 63;
    const int wid  = tid >> 6;
    const int row0 = blockIdx.y * 256;
    const int col0 = blockIdx.x * 128;
    const int wm = (wid >> 1) * 64;    // wave's 64-row slab
    const int wn = (wid & 1) * 64;     // wave's 64-col slab
    const int lr = lane & 15, kq = lane >> 4;

    const int kpb    = K / gridDim.z;  // split-K chunk
    const int kstart = blockIdx.z * kpb;
    const int NT = kpb >> 6;           // K64 tiles in this chunk

    f32x4 acc[4][4];
    #pragma unroll
    for (int i = 0; i < 4; ++i)
        #pragma unroll
        for (int j = 0; j < 4; ++j) acc[i][j] = (f32x4){0.f, 0.f, 0.f, 0.f};

    // per-lane staging source (pre-swizzled k-chunk)
    const int srow = lane >> 3;              // row within 8-row group
    const int kch  = (lane & 7) ^ srow;      // swizzled 16B k-chunk 0..7
    const short* Ag = A  + (size_t)(row0 + wid * 32 + srow) * K + kstart + kch * 8;
    const short* Bg = BT + (size_t)(col0 + wid * 16 + srow) * K + kstart + kch * 8;

    auto stage = [&](int t) {
        const int buf = t % 3;
        char* sA = smem + buf * 49152;
        char* sB = sA + 32768;
        const int k0 = t << 6;
        #pragma unroll
        for (int ii = 0; ii < 4; ++ii)      // A: 256 rows = 32 instr, 4/wave
            gload_lds16(Ag + (size_t)ii * 8 * K + k0, sA + (wid * 4 + ii) * 1024);
        #pragma unroll
        for (int ii = 0; ii < 2; ++ii)      // B: 128 rows = 16 instr, 2/wave
            gload_lds16(Bg + (size_t)ii * 8 * K + k0, sB + (wid * 2 + ii) * 1024);
    };

    stage(0);
    stage(1);
    asm volatile("s_waitcnt vmcnt(6)" ::: "memory");   // tile 0 resident
    __builtin_amdgcn_s_barrier();
    asm volatile("" ::: "memory");

    for (int t = 0; t < NT; ++t) {
        const bool more = (t + 2) < NT;
        if (more) stage(t + 2);             // uniform branch

        const char* sA = smem + (t % 3) * 49152;
        const char* sB = sA + 32768;

        #pragma unroll
        for (int ks = 0; ks < 2; ++ks) {
            bf16x8 af[4], bfv[4];
            #pragma unroll
            for (int i = 0; i < 4; ++i) {
                const int row = wm + i * 16 + lr;
                af[i] = *reinterpret_cast<const bf16x8*>(
                    sA + row * 128 + (((ks * 4 + kq) ^ (lr & 7)) * 16));
            }
            #pragma unroll
            for (int j = 0; j < 4; ++j) {
                const int row = wn + j * 16 + lr;
                bfv[j] = *reinterpret_cast<const bf16x8*>(
                    sB + row * 128 + (((ks * 4 + kq) ^ (lr & 7)) * 16));
            }
            __builtin_amdgcn_s_setprio(1);
            #pragma unroll
            for (int i = 0; i < 4; ++i)
                #pragma unroll
                for (int j = 0; j < 4; ++j)
                    acc[i][j] = __builtin_amdgcn_mfma_f32_16x16x32_bf16(
                        af[i], bfv[j], acc[i][j], 0, 0, 0);
            __builtin_amdgcn_s_setprio(0);
        }

        asm volatile("" ::: "memory");
        if (more) asm volatile("s_waitcnt vmcnt(6) lgkmcnt(0)" ::: "memory");
        else      asm volatile("s_waitcnt vmcnt(0) lgkmcnt(0)" ::: "memory");
        __builtin_amdgcn_s_barrier();
        asm volatile("" ::: "memory");
    }

    // Epilogue. D frag layout: row = (lane>>4)*4 + q, col = lane&15.
    #pragma unroll
    for (int j = 0; j < 4; ++j) {
        const int col = col0 + wn + j * 16 + lr;
        const float bv = (EPI == 0) ? bias[col] : 0.f;
        #pragma unroll
        for (int i = 0; i < 4; ++i) {
            #pragma unroll
            for (int q = 0; q < 4; ++q) {
                const int row = row0 + wm + i * 16 + kq * 4 + q;
                if (EPI == 0) {
                    float v = gelu_exact(acc[i][j][q] + bv);
                    ((short*)Cout)[(size_t)row * N + col] = f2bf(v);
                } else {
                    ((float*)Cout)[((size_t)blockIdx.z * M + row) * N + col] = acc[i][j][q];
                }
            }
        }
    }
}

// ---------------------------------------------------------------------------
// EXPERIMENT (GEMM2): faithful m201-geometry port. 256x256 tile, BK=64,
// 512 thr = 8 waves (2M x 4N), per-wave 128x64 (acc[8][4]). LDS 128KB =
// 2buf x (A 32KB + B 32KB), each tile staged as 4 half-tiles (A0,A1,B0,B1).
// 4 barrier-phases per K-tile, each: {<=8 ds_read_b128, stage half-tiles,
// barrier, lgkmcnt(0), setprio, 16 MFMA, setprio, barrier}. Tile t+1's
// staging issued at phases 1-2 of tile t; vmcnt(0) at end of phase 4 waits
// on loads issued 2-3 phases earlier (latency pre-hidden, race-free).
// Split-K via gridDim.z=2; stores bf16 partials to P0 (z=0) / P1 (z=1).
// ---------------------------------------------------------------------------
__global__ __launch_bounds__(512) void gemm_ph8(
    const short* __restrict__ A, const short* __restrict__ BT,
    short* __restrict__ P0, short* __restrict__ P1,
    int M, int N, int K)
{
    extern __shared__ __align__(16) char smem[];   // A: 2x32KB, B at +64KB

    const int tid  = threadIdx.x;
    const int lane = tid & 63;
    const int wid  = tid >> 6;
    const int row0 = blockIdx.y * 256;
    const int col0 = blockIdx.x * 256;
    const int wm = wid >> 2;           // 0..1: wave's 128-row half
    const int wn = wid & 3;            // 0..3: wave's 64-col quarter
    const int lr = lane & 15, kq = lane >> 4;

    const int kstart = blockIdx.z * (K >> 1);
    const int NT = (K >> 1) >> 6;      // K64 tiles in this half

    f32x4 acc[8][4];
    #pragma unroll
    for (int i = 0; i < 8; ++i)
        #pragma unroll
        for (int j = 0; j < 4; ++j) acc[i][j] = (f32x4){0.f, 0.f, 0.f, 0.f};

    // staging: wave wid covers rows [wid*16, wid*16+16) of each 128-row half;
    // 2 gloads of 8 rows each. Pre-swizzled source chunk (lane&7)^srow8.
    const int srow8 = lane >> 3;
    const int kchs  = (lane & 7) ^ srow8;
    const short* Asrc = A  + (size_t)(row0 + wid * 16 + srow8) * K + kstart + kchs * 8;
    const short* Bsrc = BT + (size_t)(col0 + wid * 16 + srow8) * K + kstart + kchs * 8;

    auto stA = [&](int t, int h) {
        char* d = smem + (t & 1) * 32768 + h * 16384 + wid * 2048;
        const short* s = Asrc + (size_t)(h * 128) * K + (t << 6);
        gload_lds16(s, d);
        gload_lds16(s + (size_t)8 * K, d + 1024);
    };
    auto stB = [&](int t, int h) {
        char* d = smem + 65536 + (t & 1) * 32768 + h * 16384 + wid * 2048;
        const short* s = Bsrc + (size_t)(h * 128) * K + (t << 6);
        gload_lds16(s, d);
        gload_lds16(s + (size_t)8 * K, d + 1024);
    };

    // prologue: stage tile 0 fully, drain once
    stA(0, 0); stA(0, 1); stB(0, 0); stB(0, 1);
    asm volatile("s_waitcnt vmcnt(0)" ::: "memory");
    __builtin_amdgcn_s_barrier();
    asm volatile("" ::: "memory");

    for (int t = 0; t < NT; ++t) {
        const bool more = (t + 1) < NT;
        const char* sAb = smem + (t & 1) * 32768 + wm * 16384;
        const char* sBb = smem + 65536 + (t & 1) * 32768 + (wn >> 1) * 16384;
        const int bro = (wn & 1) * 64;
        bf16x8 a0[4], a1[4], bv[4];

        // ---- phase 1: ks0, frag-rows 0-3 (8 ds_read) + stage A(t+1)
        #pragma unroll
        for (int i = 0; i < 4; ++i)
            a0[i] = *reinterpret_cast<const bf16x8*>(
                sAb + (i * 16 + lr) * 128 + ((kq ^ (lr & 7)) * 16));
        #pragma unroll
        for (int j = 0; j < 4; ++j)
            bv[j] = *reinterpret_cast<const bf16x8*>(
                sBb + (bro + j * 16 + lr) * 128 + ((kq ^ (lr & 7)) * 16));
        if (more) { stA(t + 1, 0); stA(t + 1, 1); }
        __builtin_amdgcn_s_barrier();
        asm volatile("s_waitcnt lgkmcnt(0)" ::: "memory");
        __builtin_amdgcn_sched_barrier(0);
        __builtin_amdgcn_s_setprio(1);
        #pragma unroll
        for (int i = 0; i < 4; ++i)
            #pragma unroll
            for (int j = 0; j < 4; ++j)
                acc[i][j] = __builtin_amdgcn_mfma_f32_16x16x32_bf16(a0[i], bv[j], acc[i][j], 0, 0, 0);
        __builtin_amdgcn_s_setprio(0);
        __builtin_amdgcn_s_barrier();

        // ---- phase 2: ks0, frag-rows 4-7 (4 ds_read, B reused) + stage B(t+1)
        #pragma unroll
        for (int i = 0; i < 4; ++i)
            a1[i] = *reinterpret_cast<const bf16x8*>(
                sAb + ((i + 4) * 16 + lr) * 128 + ((kq ^ (lr & 7)) * 16));
        if (more) { stB(t + 1, 0); stB(t + 1, 1); }
        __builtin_amdgcn_s_barrier();
        asm volatile("s_waitcnt lgkmcnt(0)" ::: "memory");
        __builtin_amdgcn_sched_barrier(0);
        __builtin_amdgcn_s_setprio(1);
        #pragma unroll
        for (int i = 0; i < 4; ++i)
            #pragma unroll
            for (int j = 0; j < 4; ++j)
                acc[i + 4][j] = __builtin_amdgcn_mfma_f32_16x16x32_bf16(a1[i], bv[j], acc[i + 4][j], 0, 0, 0);
        __builtin_amdgcn_s_setprio(0);
        __builtin_amdgcn_s_barrier();

        // ---- phase 3: ks1, frag-rows 0-3 (8 ds_read)
        #pragma unroll
        for (int i = 0; i < 4; ++i)
            a0[i] = *reinterpret_cast<const bf16x8*>(
                sAb + (i * 16 + lr) * 128 + (((4 + kq) ^ (lr & 7)) * 16));
        #pragma unroll
        for (int j = 0; j < 4; ++j)
            bv[j] = *reinterpret_cast<const bf16x8*>(
                sBb + (bro + j * 16 + lr) * 128 + (((4 + kq) ^ (lr & 7)) * 16));
        __builtin_amdgcn_s_barrier();
        asm volatile("s_waitcnt lgkmcnt(0)" ::: "memory");
        __builtin_amdgcn_sched_barrier(0);
        __builtin_amdgcn_s_setprio(1);
        #pragma unroll
        for (int i = 0; i < 4; ++i)
            #pragma unroll
            for (int j = 0; j < 4; ++j)
                acc[i][j] = __builtin_amdgcn_mfma_f32_16x16x32_bf16(a0[i], bv[j], acc[i][j], 0, 0, 0);
        __builtin_amdgcn_s_setprio(0);
        __builtin_amdgcn_s_barrier();

        // ---- phase 4: ks1, frag-rows 4-7 (4 ds_read); vmcnt(0) on 2-3
        //      phase-old staging before flipping buffers
        #pragma unroll
        for (int i = 0; i < 4; ++i)
            a1[i] = *reinterpret_cast<const bf16x8*>(
                sAb + ((i + 4) * 16 + lr) * 128 + (((4 + kq) ^ (lr & 7)) * 16));
        __builtin_amdgcn_s_barrier();
        asm volatile("s_waitcnt lgkmcnt(0)" ::: "memory");
        __builtin_amdgcn_sched_barrier(0);
        __builtin_amdgcn_s_setprio(1);
        #pragma unroll
        for (int i = 0; i < 4; ++i)
            #pragma unroll
            for (int j = 0; j < 4; ++j)
                acc[i + 4][j] = __builtin_amdgcn_mfma_f32_16x16x32_bf16(a1[i], bv[j], acc[i + 4][j], 0, 0, 0);
        __builtin_amdgcn_s_setprio(0);
        if (more) asm volatile("s_waitcnt vmcnt(0)" ::: "memory");
        __builtin_amdgcn_s_barrier();
        asm volatile("" ::: "memory");
    }

    // Epilogue: bf16 partial store. D frag: row=(lane>>4)*4+q, col=lane&15.
    short* P = blockIdx.z ? P1 : P0;
    #pragma unroll
    for (int j = 0; j < 4; ++j) {
        const int col = col0 + wn * 64 + j * 16 + lr;
        #pragma unroll
        for (int i = 0; i < 8; ++i) {
            #pragma unroll
            for (int q = 0; q < 4; ++q) {
                const int row = row0 + wm * 128 + i * 16 + kq * 4 + q;
                P[(size_t)row * N + col] = f2bf(acc[i][j][q]);
            }
        }
    }
}

// ---------------------------------------------------------------------------
// Combine split-K halves: h2 = gelu(p0 + p1 + bias) -> bf16 (p0 aliases h2).
// ---------------------------------------------------------------------------
__global__ __launch_bounds__(256) void gelu_combine(
    const short* __restrict__ p0, const short* __restrict__ p1,
    const float* __restrict__ bias, short* __restrict__ h2)
{
    const int i = (blockIdx.x * 256 + threadIdx.x) * 4;
    const short4 v0 = *reinterpret_cast<const short4*>(&p0[i]);
    const short4 v1 = *reinterpret_cast<const short4*>(&p1[i]);
    const int col = i & (H_SZ - 1);
    short4 o;
    o.x = f2bf(gelu_exact(bf2f(v0.x) + bf2f(v1.x) + bias[col + 0]));
    o.y = f2bf(gelu_exact(bf2f(v0.y) + bf2f(v1.y) + bias[col + 1]));
    o.z = f2bf(gelu_exact(bf2f(v0.z) + bf2f(v1.z) + bias[col + 2]));
    o.w = f2bf(gelu_exact(bf2f(v0.w) + bf2f(v1.w) + bias[col + 3]));
    *reinterpret_cast<short4*>(&h2[i]) = o;
}

// ---------------------------------------------------------------------------
// expmap0: u = sum_z up[z] + b3 -> x_hyp (bf16) ; rowb2 = tanh(||u||)^2.
// ---------------------------------------------------------------------------
__global__ __launch_bounds__(128) void expmap_kernel(
    const float* __restrict__ up, const float* __restrict__ b3,
    short* __restrict__ xhb, float* __restrict__ rowb2)
{
    const int b = blockIdx.x;
    const int d = threadIdx.x;
    float u = b3[d];
    #pragma unroll
    for (int z = 0; z < 16; ++z)
        u += up[((size_t)z * B_SZ + b) * D_SZ + d];

    float s = u * u;
    #pragma unroll
    for (int off = 32; off; off >>= 1) s += __shfl_down(s, off);
    __shared__ float part[2];
    if ((d & 63) == 0) part[d >> 6] = s;
    __syncthreads();
    const float n2 = part[0] + part[1];

    const float n = fmaxf(sqrtf(n2), 1e-15f);
    const float t = tanhf(n);
    xhb[(size_t)b * D_SZ + d] = f2bf(u * (t / n));
    if (d == 0) rowb2[b] = t * t;
}

// ---------------------------------------------------------------------------
// MFMA pairwise hyperbolic distance -> logits.
// Tile 128(b) x 64(p), 256 threads = 4 waves (2b x 2p of 64x32). K = 128.
// ---------------------------------------------------------------------------
__global__ __launch_bounds__(256) void dist_mfma(
    const short* __restrict__ xhb, const short* __restrict__ protob,
    const float* __restrict__ rowb2, const float* __restrict__ a2gp,
    float* __restrict__ logits)
{
    __shared__ __align__(16) char xs[128 * 256];  // 32 KB [row][256B]
    __shared__ __align__(16) char ps[64 * 256];   // 16 KB

    const int tid  = threadIdx.x;
    const int lane = tid & 63, wid = tid >> 6;
    const int pt = blockIdx.x * 64;
    const int bt = blockIdx.y * 128;
    const int wm = (wid >> 1) * 64;    // b slab
    const int wn = (wid & 1) * 32;     // p slab
    const int lr = lane & 15, kq = lane >> 4;

    // staging: each 1KB gload covers 4 rows x 16 chunks; lane = rl*16 + c
    const int rl = lane >> 4, c = lane & 15;
    #pragma unroll
    for (int i = 0; i < 8; ++i) {          // xh: 32 gloads, 8/wave
        const int row = wid * 32 + i * 4 + rl;
        const int lc  = (c & 8) | ((c & 7) ^ (row & 7));
        gload_lds16(xhb + (size_t)(bt + row) * D_SZ + lc * 8,
                    xs + (wid * 8 + i) * 1024);
    }
    #pragma unroll
    for (int i = 0; i < 4; ++i) {          // proto: 16 gloads, 4/wave
        const int row = wid * 16 + i * 4 + rl;
        const int lc  = (c & 8) | ((c & 7) ^ (row & 7));
        gload_lds16(protob + (size_t)(pt + row) * D_SZ + lc * 8,
                    ps + (wid * 4 + i) * 1024);
    }
    __syncthreads();

    f32x4 acc[4][2];
    #pragma unroll
    for (int i = 0; i < 4; ++i)
        #pragma unroll
        for (int j = 0; j < 2; ++j) acc[i][j] = (f32x4){0.f, 0.f, 0.f, 0.f};

    #pragma unroll
    for (int ks = 0; ks < 4; ++ks) {
        const int kslot = ks * 4 + kq;
        bf16x8 af[4], bfv[2];
        #pragma unroll
        for (int i = 0; i < 4; ++i) {
            const int row = wm + i * 16 + lr;
            const int ph = (kslot & 8) | ((kslot & 7) ^ (row & 7));
            af[i] = *reinterpret_cast<const bf16x8*>(xs + row * 256 + ph * 16);
        }
        #pragma unroll
        for (int j = 0; j < 2; ++j) {
            const int row = wn + j * 16 + lr;
            const int ph = (kslot & 8) | ((kslot & 7) ^ (row & 7));
            bfv[j] = *reinterpret_cast<const bf16x8*>(ps + row * 256 + ph * 16);
        }
        #pragma unroll
        for (int i = 0; i < 4; ++i)
            #pragma unroll
            for (int j = 0; j < 2; ++j)
                acc[i][j] = __builtin_amdgcn_mfma_f32_16x16x32_bf16(
                    af[i], bfv[j], acc[i][j], 0, 0, 0);
    }

    // epilogue: hyperbolic formula, fp32. D frag: row=(lane>>4)*4+q, col=lane&15
    #pragma unroll
    for (int j = 0; j < 2; ++j) {
        const int p = pt + wn + j * 16 + lr;
        if (p < P_SZ) {
            const float a2 = a2gp[p];
            #pragma unroll
            for (int i = 0; i < 4; ++i) {
                #pragma unroll
                for (int q = 0; q < 4; ++q) {
                    const int b = bt + wm + i * 16 + kq * 4 + q;
                    const float b2 = rowb2[b];
                    const float ab = -acc[i][j][q];
                    const float alpha = 1.f + 2.f * ab + b2;
                    const float beta  = 1.f - a2;
                    const float gamma = 1.f + 2.f * ab + a2 * b2;
                    const float num = alpha * alpha * a2 + 2.f * alpha * beta * ab + beta * beta * b2;
                    const float m2 = num / (gamma * gamma);
                    const float mn = sqrtf(fmaxf(m2, 0.f));
                    const float arg = fminf(mn, 0.99999f);              // TANH_CLIP
                    const float dist = logf((1.f + arg) / (1.f - arg)); // 2*atanh
                    logits[(size_t)b * P_SZ + p] = -10.f * dist;        // -dist/TEMP
                }
            }
        }
    }
}

// ---------------------------------------------------------------------------
// Per-row argmax (first-max tie-break) + logmap0(proto[pred]).
// ---------------------------------------------------------------------------
__global__ __launch_bounds__(256) void head_kernel(
    const float* __restrict__ logits, const float* __restrict__ proto,
    float* __restrict__ fb)
{
    const int b = blockIdx.x;
    const int tid = threadIdx.x;

    float best = -INFINITY; int bi = 0;
    for (int p = tid; p < P_SZ; p += 256) {
        const float v = logits[(size_t)b * P_SZ + p];
        if (v > best) { best = v; bi = p; }
    }
    __shared__ float bv[256];
    __shared__ int   bidx[256];
    bv[tid] = best; bidx[tid] = bi;
    __syncthreads();
    for (int s = 128; s; s >>= 1) {
        if (tid < s) {
            const float ov = bv[tid + s]; const int oi = bidx[tid + s];
            if (ov > bv[tid] || (ov == bv[tid] && oi < bidx[tid])) { bv[tid] = ov; bidx[tid] = oi; }
        }
        __syncthreads();
    }
    const int pred = bidx[0];
    __syncthreads();

    float y = 0.f;
    if (tid < 128) y = proto[(size_t)pred * D_SZ + tid];
    bv[tid] = y * y;
    __syncthreads();
    for (int s = 128; s; s >>= 1) {
        if (tid < s) bv[tid] += bv[tid + s];
        __syncthreads();
    }
    const float n2 = bv[0];
    if (tid < 128) {
        const float n = fmaxf(sqrtf(n2), 1e-15f);
        const float arg = fminf(n, 0.99999f);
        const float at = 0.5f * logf((1.f + arg) / (1.f - arg));
        fb[(size_t)b * D_SZ + tid] = at * (y / n);
    }
}

extern "C" void kernel_launch(void* const* d_in, const int* in_sizes, int n_in,
                              void* d_out, int out_size, void* d_ws, size_t ws_size,
                              hipStream_t stream)
{
    const float* x     = (const float*)d_in[0];
    const float* W1    = (const float*)d_in[1];
    const float* b1    = (const float*)d_in[2];
    const float* W2    = (const float*)d_in[3];
    const float* b2v   = (const float*)d_in[4];
    const float* W3    = (const float*)d_in[5];
    const float* b3    = (const float*)d_in[6];
    const float* proto = (const float*)d_in[7];

    float* logits = (float*)d_out;                      // 2048*1000
    float* fb     = logits + (size_t)B_SZ * P_SZ;       // 2048*128

    // workspace layout (bf16 stored as short)
    short* xb     = (short*)d_ws;                        //  2048*1024
    short* w1t    = xb    + (size_t)B_SZ * DIN;          //  4096*1024
    short* w2t    = w1t   + (size_t)H_SZ * DIN;          //  4096*4096
    short* w3t    = w2t   + (size_t)H_SZ * H_SZ;         //   128*4096
    short* h1     = w3t   + (size_t)D_SZ * H_SZ;         //  2048*4096 (bf16)
    short* h2     = h1    + (size_t)B_SZ * H_SZ;         //  2048*4096 (= P0)
    short* xhb    = h2    + (size_t)B_SZ * H_SZ;         //  2048*128 bf16
    short* protob = xhb   + (size_t)B_SZ * D_SZ;         //  1024*128 bf16
    float* rowb2  = (float*)(protob + (size_t)PPAD * D_SZ); // 2048 fp32
    float* a2gp   = rowb2 + B_SZ;                        //  1024 fp32
    short* gp1    = (short*)(a2gp + PPAD);               //  2048*4096 bf16 (P1)
    // up aliases h1 (dead after GEMM2): 16 slices * 2048*128 fp32 = 16 MB
    float* up     = (float*)h1;

    static_cast<void>(hipFuncSetAttribute(
        reinterpret_cast<const void*>(&gemm_big<0>),
        hipFuncAttributeMaxDynamicSharedMemorySize, 3 * 49152));
    static_cast<void>(hipFuncSetAttribute(
        reinterpret_cast<const void*>(&gemm_big<1>),
        hipFuncAttributeMaxDynamicSharedMemorySize, 3 * 49152));
    static_cast<void>(hipFuncSetAttribute(
        reinterpret_cast<const void*>(&gemm_ph8),
        hipFuncAttributeMaxDynamicSharedMemorySize, 131072));

    // --- fused precision prep (1 launch: cvt + 3 transposes + protos) ---
    prep_kernel<<<7808, 256, 0, stream>>>(x, xb, W1, w1t, W2, w2t, W3, w3t,
                                          proto, protob, a2gp);

    // --- MLP ---
    // GEMM1: proven round-4/6 structure
    gemm_big<0><<<dim3(H_SZ / 128, B_SZ / 256), 512, 3 * 49152, stream>>>(
        xb, w1t, b1, h1, B_SZ, H_SZ, DIN);
    // GEMM2: 256^2 4-phase experiment, split-K=2, bf16 partials (P0 = h2)
    gemm_ph8<<<dim3(H_SZ / 256, B_SZ / 256, 2), 512, 131072, stream>>>(
        h1, w2t, h2, gp1, B_SZ, H_SZ, H_SZ);
    gelu_combine<<<(B_SZ * H_SZ) / 1024, 256, 0, stream>>>(h2, gp1, b2v, h2);
    // GEMM3: split-K=16, per-z slices (no atomics); up aliases h1 (h1 dead now)
    gemm_big<1><<<dim3(1, B_SZ / 256, 16), 512, 3 * 49152, stream>>>(
        h2, w3t, nullptr, up, B_SZ, D_SZ, H_SZ);

    // --- hyperbolic head ---
    expmap_kernel<<<B_SZ, 128, 0, stream>>>(up, b3, xhb, rowb2);
    dist_mfma<<<dim3(PPAD / 64, B_SZ / 128), 256, 0, stream>>>(
        xhb, protob, rowb2, a2gp, logits);
    head_kernel<<<B_SZ, 256, 0, stream>>>(logits, proto, fb);
}